// Round 3
// baseline (2009.043 us; speedup 1.0000x reference)
//
#include <hip/hip_runtime.h>
#include <math.h>

#define DIM 64
#define HEADS 8
#define HIDDEN 256

// ---------------- prep: fold linear chains into combined weights ----------------
// Waug[64][80] = [w_in | w_in@w_att_u | w_in@w_att_v], baug[80] matching biases.
// wcc[2][8] = w_edge@w_att_e, bcc[8] = b_edge@w_att_e + b_att_e.
// w1t[256][64] = transpose(w_ff1) for contiguous per-hidden rows.
__global__ void prep_kernel(
    const float* __restrict__ w_in, const float* __restrict__ b_in,
    const float* __restrict__ w_edge, const float* __restrict__ b_edge,
    const float* __restrict__ w_att_u, const float* __restrict__ b_att_u,
    const float* __restrict__ w_att_v,
    const float* __restrict__ w_att_e, const float* __restrict__ b_att_e,
    const float* __restrict__ w_ff1,
    float* __restrict__ Waug, float* __restrict__ baug,
    float* __restrict__ wcc, float* __restrict__ bcc,
    float* __restrict__ w1t)
{
  int t = threadIdx.x; // 256 threads
  if (t < 64) {
    for (int j = 0; j < 64; ++j) Waug[t*80 + j] = w_in[t*64 + j];
    for (int hh = 0; hh < 8; ++hh) {
      float a = 0.f, b = 0.f;
      for (int j = 0; j < 64; ++j) {
        float w = w_in[t*64 + j];
        a += w * w_att_u[j*8 + hh];
        b += w * w_att_v[j*8 + hh];
      }
      Waug[t*80 + 64 + hh] = a;
      Waug[t*80 + 72 + hh] = b;
    }
  } else if (t < 128) {
    int j = t - 64;
    baug[j] = b_in[j];
  } else if (t < 136) {
    int hh = t - 128;
    float a = b_att_u[hh];
    for (int k = 0; k < 64; ++k) a += b_in[k] * w_att_u[k*8 + hh];
    baug[64 + hh] = a;
  } else if (t < 144) {
    int hh = t - 136;
    float a = 0.f;
    for (int k = 0; k < 64; ++k) a += b_in[k] * w_att_v[k*8 + hh];
    baug[72 + hh] = a;
  } else if (t < 160) {
    int c = (t - 144) >> 3, hh = (t - 144) & 7;
    float a = 0.f;
    for (int j = 0; j < 64; ++j) a += w_edge[c*64 + j] * w_att_e[j*8 + hh];
    wcc[c*8 + hh] = a;
  } else if (t < 168) {
    int hh = t - 160;
    float a = b_att_e[hh];
    for (int j = 0; j < 64; ++j) a += b_edge[j] * w_att_e[j*8 + hh];
    bcc[hh] = a;
  }
  // all 256 threads: transpose w_ff1 [64][256] -> w1t [256][64]
  for (int k = 0; k < 64; ++k) w1t[t*64 + k] = w_ff1[k*256 + t];
}

// ---------------- node GEMM: [N,64] @ [64,80] -> h, su, sv ----------------
// 4 threads per node; thread (n,p) owns output columns [20p, 20p+20).
__global__ __launch_bounds__(256) void node_gemm_kernel(
    const float* __restrict__ x,
    const float* __restrict__ Waug, const float* __restrict__ baug,
    float* __restrict__ hbuf, float* __restrict__ subuf, float* __restrict__ svbuf,
    int n_nodes)
{
  const int tid = threadIdx.x;
  const int nl = tid >> 2, p = tid & 3;
  const long n = (long)blockIdx.x * 64 + nl;
  if (n >= n_nodes) return;

  float xr[64];
  const float4* xp = (const float4*)(x + n*DIM);
  #pragma unroll
  for (int q = 0; q < 16; ++q) {
    float4 v = xp[q];
    xr[4*q] = v.x; xr[4*q+1] = v.y; xr[4*q+2] = v.z; xr[4*q+3] = v.w;
  }
  const int cb = p * 20;
  float acc[20];
  #pragma unroll
  for (int q = 0; q < 5; ++q) {
    float4 v = *(const float4*)(baug + cb + 4*q);
    acc[4*q] = v.x; acc[4*q+1] = v.y; acc[4*q+2] = v.z; acc[4*q+3] = v.w;
  }
  for (int k = 0; k < 64; ++k) {
    float xv = xr[k];
    const float4* wr = (const float4*)(Waug + k*80 + cb);  // 4 uniform addrs per wave
    #pragma unroll
    for (int q = 0; q < 5; ++q) {
      float4 w = wr[q];
      acc[4*q]   += xv * w.x;
      acc[4*q+1] += xv * w.y;
      acc[4*q+2] += xv * w.z;
      acc[4*q+3] += xv * w.w;
    }
  }
  if (p < 3) {
    float4* hp = (float4*)(hbuf + n*DIM + cb);
    #pragma unroll
    for (int q = 0; q < 5; ++q)
      hp[q] = make_float4(acc[4*q], acc[4*q+1], acc[4*q+2], acc[4*q+3]);
  } else {
    // cols 60..63 -> h, 64..71 -> su, 72..79 -> sv
    *(float4*)(hbuf + n*DIM + 60) = make_float4(acc[0], acc[1], acc[2], acc[3]);
    float4* sup = (float4*)(subuf + n*8);
    sup[0] = make_float4(acc[4], acc[5], acc[6], acc[7]);
    sup[1] = make_float4(acc[8], acc[9], acc[10], acc[11]);
    float4* svp = (float4*)(svbuf + n*8);
    svp[0] = make_float4(acc[12], acc[13], acc[14], acc[15]);
    svp[1] = make_float4(acc[16], acc[17], acc[18], acc[19]);
  }
}

// ---------------- CSR build ----------------
__global__ void hist_kernel(const int* __restrict__ dst, int* __restrict__ deg, int n_edges) {
  int i = blockIdx.x * blockDim.x + threadIdx.x;
  if (i < n_edges) atomicAdd(&deg[dst[i]], 1);
}

// per-node contiguous region allocation; order irrelevant -> no global scan needed
__global__ void alloc_kernel(const int* __restrict__ deg, int* __restrict__ off,
                             int* __restrict__ counter, int n_nodes) {
  int i = blockIdx.x * blockDim.x + threadIdx.x;
  int lane = threadIdx.x & 63;
  int d = (i < n_nodes) ? deg[i] : 0;
  int pre = d;
  #pragma unroll
  for (int s = 1; s < 64; s <<= 1) {
    int v = __shfl_up(pre, s, 64);
    if (lane >= s) pre += v;
  }
  int tot = __shfl(pre, 63, 64);
  int base = 0;
  if (lane == 0) base = atomicAdd(counter, tot);
  base = __shfl(base, 0, 64);
  if (i < n_nodes) off[i] = base + pre - d;
}

__global__ void scatter_kernel(const int* __restrict__ dst, const int* __restrict__ off,
                               int* __restrict__ pos, int* __restrict__ csr, int n_edges) {
  int i = blockIdx.x * blockDim.x + threadIdx.x;
  if (i < n_edges) {
    int d = dst[i];
    int p = atomicAdd(&pos[d], 1);
    csr[off[d] + p] = i;
  }
}

// ---------------- attention gather: one wave per dst node ----------------
__device__ __forceinline__ float sel8(float v0, float v1, float v2, float v3,
                                      float v4, float v5, float v6, float v7, int idx) {
  float a0 = (idx & 1) ? v1 : v0;
  float a1 = (idx & 1) ? v3 : v2;
  float a2 = (idx & 1) ? v5 : v4;
  float a3 = (idx & 1) ? v7 : v6;
  float b0 = (idx & 2) ? a1 : a0;
  float b1 = (idx & 2) ? a3 : a2;
  return (idx & 4) ? b1 : b0;
}

__global__ __launch_bounds__(256) void attn_kernel(
    const int* __restrict__ src, const int* __restrict__ csr,
    const int* __restrict__ off, const int* __restrict__ deg,
    const float* __restrict__ edge_feat,
    const float* __restrict__ hbuf, const float* __restrict__ subuf,
    const float* __restrict__ svbuf,
    const float* __restrict__ wcc, const float* __restrict__ bcc,
    float* __restrict__ agg, int n_nodes)
{
  __shared__ float pbuf[4][64][8];
  __shared__ int   sbuf[4][64];
  const int wid = threadIdx.x >> 6;
  const int lane = threadIdx.x & 63;
  const long n = (long)blockIdx.x * 4 + wid;
  if (n >= n_nodes) return;
  const int ebase = off[n];
  const int d = deg[n];
  const int hsel = lane & 7;   // head owning output dim `lane` (h.reshape(n, hd, H))

  float svn[8], c0v[8], c1v[8], cbv[8];
  {
    const float4* svp = (const float4*)(svbuf + n*8);
    float4 s0 = svp[0], s1 = svp[1];
    svn[0]=s0.x; svn[1]=s0.y; svn[2]=s0.z; svn[3]=s0.w;
    svn[4]=s1.x; svn[5]=s1.y; svn[6]=s1.z; svn[7]=s1.w;
    #pragma unroll
    for (int hh = 0; hh < 8; ++hh) {
      c0v[hh] = wcc[hh]; c1v[hh] = wcc[8+hh]; cbv[hh] = bcc[hh];
    }
  }
  float m8[8], den8[8];
  #pragma unroll
  for (int hh = 0; hh < 8; ++hh) { m8[hh] = -INFINITY; den8[hh] = 0.f; }
  float msg = 0.f;

  for (int c0 = 0; c0 < d; c0 += 64) {
    const int cnt = min(64, d - c0);
    float sc[8];
    int sid = 0;
    if (lane < cnt) {
      const int eid = csr[ebase + c0 + lane];
      sid = src[eid];
      const float2 ef = *(const float2*)(edge_feat + (long)eid*2);
      const float4* sup = (const float4*)(subuf + (long)sid*8);
      float4 u0 = sup[0], u1 = sup[1];
      float suv[8] = {u0.x,u0.y,u0.z,u0.w,u1.x,u1.y,u1.z,u1.w};
      #pragma unroll
      for (int hh = 0; hh < 8; ++hh) {
        float v = suv[hh] + svn[hh] + ef.x*c0v[hh] + ef.y*c1v[hh] + cbv[hh];
        sc[hh] = (v > 0.f) ? v : 0.2f*v;   // leaky_relu 0.2
      }
    } else {
      #pragma unroll
      for (int hh = 0; hh < 8; ++hh) sc[hh] = -INFINITY;
    }
    // chunk max per head, xor-butterfly => bit-identical replicated across lanes
    float cm[8];
    #pragma unroll
    for (int hh = 0; hh < 8; ++hh) cm[hh] = sc[hh];
    #pragma unroll
    for (int sft = 32; sft >= 1; sft >>= 1) {
      #pragma unroll
      for (int hh = 0; hh < 8; ++hh)
        cm[hh] = fmaxf(cm[hh], __shfl_xor(cm[hh], sft, 64));
    }
    // online softmax update
    float f[8], pv[8];
    #pragma unroll
    for (int hh = 0; hh < 8; ++hh) {
      float nm = fmaxf(m8[hh], cm[hh]);
      f[hh] = __expf(m8[hh] - nm);       // first chunk: exp(-inf)=0 (state is 0 anyway)
      pv[hh] = __expf(sc[hh] - nm);      // idle lanes: exp(-inf)=0
      m8[hh] = nm;
    }
    if (lane < cnt) {
      float4* pp = (float4*)&pbuf[wid][lane][0];
      pp[0] = make_float4(pv[0], pv[1], pv[2], pv[3]);
      pp[1] = make_float4(pv[4], pv[5], pv[6], pv[7]);
      sbuf[wid][lane] = sid;
    }
    // chunk denominator
    float q[8];
    #pragma unroll
    for (int hh = 0; hh < 8; ++hh) q[hh] = pv[hh];
    #pragma unroll
    for (int sft = 32; sft >= 1; sft >>= 1) {
      #pragma unroll
      for (int hh = 0; hh < 8; ++hh)
        q[hh] += __shfl_xor(q[hh], sft, 64);
    }
    #pragma unroll
    for (int hh = 0; hh < 8; ++hh) den8[hh] = den8[hh]*f[hh] + q[hh];
    msg *= sel8(f[0],f[1],f[2],f[3],f[4],f[5],f[6],f[7], hsel);

    // wave-private LDS: waitcnt is sufficient (no cross-wave sharing, no barrier)
    asm volatile("s_waitcnt lgkmcnt(0)" ::: "memory");

    // message accumulation: lane j owns dim j; coalesced 256B h-row reads
    int e2 = 0;
    for (; e2 + 4 <= cnt; e2 += 4) {
      int s0 = sbuf[wid][e2],   s1 = sbuf[wid][e2+1];
      int s2 = sbuf[wid][e2+2], s3 = sbuf[wid][e2+3];
      float p0 = pbuf[wid][e2][hsel],   p1 = pbuf[wid][e2+1][hsel];
      float p2 = pbuf[wid][e2+2][hsel], p3 = pbuf[wid][e2+3][hsel];
      float h0 = hbuf[(long)s0*DIM + lane];
      float h1 = hbuf[(long)s1*DIM + lane];
      float h2 = hbuf[(long)s2*DIM + lane];
      float h3 = hbuf[(long)s3*DIM + lane];
      msg += h0*p0; msg += h1*p1; msg += h2*p2; msg += h3*p3;
    }
    for (; e2 < cnt; ++e2) {
      int s0 = sbuf[wid][e2];
      float p0 = pbuf[wid][e2][hsel];
      msg += hbuf[(long)s0*DIM + lane] * p0;
    }
  }
  float den = sel8(den8[0],den8[1],den8[2],den8[3],den8[4],den8[5],den8[6],den8[7], hsel);
  den = fmaxf(den, 1e-12f);
  agg[n*DIM + lane] = msg / den;
}

// ---------------- FFN: gelu(agg@w1+b1)@w2+b2 ----------------
// 4 threads per node; thread (n,p) owns hidden slice [64p, 64p+64) through both
// GEMMs; partial 64-dim outputs reduced through LDS (pacc[d][tid]: bank=tid%32,
// 2 lanes/bank = conflict-free).
__global__ __launch_bounds__(128) void ffn_kernel(
    const float* __restrict__ agg,
    const float* __restrict__ w1t, const float* __restrict__ b1,
    const float* __restrict__ w2, const float* __restrict__ b2,
    float* __restrict__ out, int n_nodes)
{
  __shared__ float pacc[64][128];   // [d][n_local*4 + p]
  const int tid = threadIdx.x;
  const int nl = tid >> 2, p = tid & 3;
  const long n = (long)blockIdx.x * 32 + nl;

  float acc[64];
  #pragma unroll
  for (int i = 0; i < 64; ++i) acc[i] = 0.f;

  if (n < n_nodes) {
    float xr[64];
    const float4* xp = (const float4*)(agg + n*DIM);
    #pragma unroll
    for (int q = 0; q < 16; ++q) {
      float4 v = xp[q];
      xr[4*q] = v.x; xr[4*q+1] = v.y; xr[4*q+2] = v.z; xr[4*q+3] = v.w;
    }
    const int jbase = p * 64;
    for (int jj = 0; jj < 64; ++jj) {
      const int j = jbase + jj;
      float hid = b1[j];
      const float4* w1r = (const float4*)(w1t + j*DIM);   // 4 uniform addrs/wave
      #pragma unroll
      for (int q = 0; q < 16; ++q) {
        float4 w = w1r[q];
        hid += xr[4*q]*w.x + xr[4*q+1]*w.y + xr[4*q+2]*w.z + xr[4*q+3]*w.w;
      }
      // exact gelu (matches jax approximate=False)
      hid = 0.5f * hid * (1.0f + erff(hid * 0.70710678118654752f));
      const float4* w2r = (const float4*)(w2 + j*DIM);    // 4 uniform addrs/wave
      #pragma unroll
      for (int q = 0; q < 16; ++q) {
        float4 w = w2r[q];
        acc[4*q]   += hid * w.x;
        acc[4*q+1] += hid * w.y;
        acc[4*q+2] += hid * w.z;
        acc[4*q+3] += hid * w.w;
      }
    }
  }
  // write partials (conflict-free: bank = tid % 32)
  #pragma unroll
  for (int d = 0; d < 64; ++d) pacc[d][tid] = acc[d];
  __syncthreads();
  // reduce: thread (node nl, quarter p) sums 4 partials for dims [16p, 16p+16)
  if (n < n_nodes) {
    #pragma unroll
    for (int di = 0; di < 16; ++di) {
      const int d = p*16 + di;
      float4 v = *(const float4*)&pacc[d][nl*4];
      out[n*DIM + d] = v.x + v.y + v.z + v.w + b2[d];
    }
  }
}

// ---------------- launch ----------------
extern "C" void kernel_launch(void* const* d_in, const int* in_sizes, int n_in,
                              void* d_out, int out_size, void* d_ws, size_t ws_size,
                              hipStream_t stream)
{
  const float* x         = (const float*)d_in[0];
  const float* edge_feat = (const float*)d_in[1];
  const float* w_in      = (const float*)d_in[2];
  const float* b_in      = (const float*)d_in[3];
  const float* w_edge    = (const float*)d_in[4];
  const float* b_edge    = (const float*)d_in[5];
  const float* w_att_u   = (const float*)d_in[6];
  const float* b_att_u   = (const float*)d_in[7];
  const float* w_att_v   = (const float*)d_in[8];
  const float* w_att_e   = (const float*)d_in[9];
  const float* b_att_e   = (const float*)d_in[10];
  const float* w_ff1     = (const float*)d_in[11];
  const float* b_ff1     = (const float*)d_in[12];
  const float* w_ff2     = (const float*)d_in[13];
  const float* b_ff2     = (const float*)d_in[14];
  const int*   src       = (const int*)d_in[15];
  const int*   dst       = (const int*)d_in[16];
  float* out = (float*)d_out;

  const int n_nodes = in_sizes[0] / DIM;
  const int n_edges = in_sizes[15];

  char* p = (char*)d_ws;
  auto alloc_f = [&](size_t cnt) { float* r = (float*)p; p += ((cnt*4 + 255) & ~(size_t)255); return r; };
  auto alloc_i = [&](size_t cnt) { int* r = (int*)p;   p += ((cnt*4 + 255) & ~(size_t)255); return r; };
  float* Waug  = alloc_f(64*80);
  float* baug  = alloc_f(80);
  float* wcc   = alloc_f(16);
  float* bcc   = alloc_f(8);
  float* w1t   = alloc_f(256*64);
  float* hbuf  = alloc_f((size_t)n_nodes*DIM);
  float* subuf = alloc_f((size_t)n_nodes*8);
  float* svbuf = alloc_f((size_t)n_nodes*8);
  float* aggb  = alloc_f((size_t)n_nodes*DIM);
  int* deg     = alloc_i(n_nodes);
  int* pos     = alloc_i(n_nodes);
  int* counter = alloc_i(64);
  int* offb    = alloc_i(n_nodes);
  int* csr     = alloc_i(n_edges);

  // zero deg, pos, counter in one shot (they are contiguous in the layout)
  hipMemsetAsync(deg, 0, (size_t)((char*)offb - (char*)deg), stream);

  hipLaunchKernelGGL(prep_kernel, dim3(1), dim3(256), 0, stream,
      w_in, b_in, w_edge, b_edge, w_att_u, b_att_u, w_att_v, w_att_e, b_att_e,
      w_ff1, Waug, baug, wcc, bcc, w1t);

  hipLaunchKernelGGL(node_gemm_kernel, dim3((n_nodes+63)/64), dim3(256), 0, stream,
      x, Waug, baug, hbuf, subuf, svbuf, n_nodes);

  hipLaunchKernelGGL(hist_kernel, dim3((n_edges+255)/256), dim3(256), 0, stream,
      dst, deg, n_edges);
  hipLaunchKernelGGL(alloc_kernel, dim3((n_nodes+255)/256), dim3(256), 0, stream,
      deg, offb, counter, n_nodes);
  hipLaunchKernelGGL(scatter_kernel, dim3((n_edges+255)/256), dim3(256), 0, stream,
      dst, offb, pos, csr, n_edges);

  hipLaunchKernelGGL(attn_kernel, dim3((n_nodes+3)/4), dim3(256), 0, stream,
      src, csr, offb, deg, edge_feat, hbuf, subuf, svbuf, wcc, bcc, aggb, n_nodes);

  hipLaunchKernelGGL(ffn_kernel, dim3((n_nodes+31)/32), dim3(128), 0, stream,
      aggb, w1t, b_ff1, w_ff2, b_ff2, out, n_nodes);
}

// Round 4
// 661.171 us; speedup vs baseline: 3.0386x; 3.0386x over previous
//
#include <hip/hip_runtime.h>
#include <math.h>

#define DIM 64
#define HEADS 8
#define HIDDEN 256

// readlane: broadcast lane `srcLane`'s value to all lanes (srcLane must be wave-uniform)
__device__ __forceinline__ float lane_bcast(float v, int srcLane) {
  return __int_as_float(__builtin_amdgcn_readlane(__float_as_int(v), srcLane));
}

// ---------------- prep: fold linear chains into combined weights ----------------
// Waug[64][80] = [w_in | w_in@w_att_u | w_in@w_att_v], baug[80] matching biases.
// wcc[2][8] = w_edge@w_att_e, bcc[8] = b_edge@w_att_e + b_att_e.
__global__ void prep_kernel(
    const float* __restrict__ w_in, const float* __restrict__ b_in,
    const float* __restrict__ w_edge, const float* __restrict__ b_edge,
    const float* __restrict__ w_att_u, const float* __restrict__ b_att_u,
    const float* __restrict__ w_att_v,
    const float* __restrict__ w_att_e, const float* __restrict__ b_att_e,
    float* __restrict__ Waug, float* __restrict__ baug,
    float* __restrict__ wcc, float* __restrict__ bcc)
{
  int t = threadIdx.x; // 256 threads
  if (t < 64) {
    for (int j = 0; j < 64; ++j) Waug[t*80 + j] = w_in[t*64 + j];
    for (int hh = 0; hh < 8; ++hh) {
      float a = 0.f, b = 0.f;
      for (int j = 0; j < 64; ++j) {
        float w = w_in[t*64 + j];
        a += w * w_att_u[j*8 + hh];
        b += w * w_att_v[j*8 + hh];
      }
      Waug[t*80 + 64 + hh] = a;
      Waug[t*80 + 72 + hh] = b;
    }
  } else if (t < 128) {
    int j = t - 64;
    baug[j] = b_in[j];
  } else if (t < 136) {
    int hh = t - 128;
    float a = b_att_u[hh];
    for (int k = 0; k < 64; ++k) a += b_in[k] * w_att_u[k*8 + hh];
    baug[64 + hh] = a;
  } else if (t < 144) {
    int hh = t - 136;
    float a = 0.f;
    for (int k = 0; k < 64; ++k) a += b_in[k] * w_att_v[k*8 + hh];
    baug[72 + hh] = a;
  } else if (t < 160) {
    int c = (t - 144) >> 3, hh = (t - 144) & 7;
    float a = 0.f;
    for (int j = 0; j < 64; ++j) a += w_edge[c*64 + j] * w_att_e[j*8 + hh];
    wcc[c*8 + hh] = a;
  } else if (t < 168) {
    int hh = t - 160;
    float a = b_att_e[hh];
    for (int j = 0; j < 64; ++j) a += b_edge[j] * w_att_e[j*8 + hh];
    bcc[hh] = a;
  }
}

// ---------------- node GEMM: [N,64] @ [64,80] -> h, su, sv ----------------
// Wave per 8 nodes. Lane owns output column `lane` (h) and column 64+lane
// (su|sv, lanes 0..15). x broadcast via v_readlane (k is wave-uniform SGPR).
// Registers: xr[8]+acc[8]+acc2[8] ~ 35 VGPR, no spill.
__global__ __launch_bounds__(256) void node_gemm_kernel(
    const float* __restrict__ x,
    const float* __restrict__ Waug, const float* __restrict__ baug,
    float* __restrict__ hbuf, float* __restrict__ subuf, float* __restrict__ svbuf,
    int n_nodes)
{
  const int wid = threadIdx.x >> 6;
  const int lane = threadIdx.x & 63;
  const long nbase = (long)blockIdx.x * 32 + wid * 8;

  float xr[8];
  #pragma unroll
  for (int m = 0; m < 8; ++m) {
    long n = nbase + m; if (n >= n_nodes) n = n_nodes - 1;
    xr[m] = x[n*DIM + lane];          // coalesced 256B row read
  }
  const float bmain = baug[lane];
  const float bext  = (lane < 16) ? baug[64 + lane] : 0.f;
  float acc[8], acc2[8];
  #pragma unroll
  for (int m = 0; m < 8; ++m) { acc[m] = bmain; acc2[m] = 0.f; }

  #pragma unroll 16
  for (int k = 0; k < 64; ++k) {
    float wmain = Waug[k*80 + lane];                       // coalesced
    float wext  = (lane < 16) ? Waug[k*80 + 64 + lane] : 0.f;
    #pragma unroll
    for (int m = 0; m < 8; ++m) {
      float xk = lane_bcast(xr[m], k);
      acc[m]  += xk * wmain;
      acc2[m] += xk * wext;
    }
  }
  #pragma unroll
  for (int m = 0; m < 8; ++m) {
    long n = nbase + m;
    if (n >= n_nodes) continue;
    hbuf[n*DIM + lane] = acc[m];
    if (lane < 8)       subuf[n*8 + lane]     = acc2[m] + bext;
    else if (lane < 16) svbuf[n*8 + lane - 8] = acc2[m] + bext;
  }
}

// ---------------- CSR build ----------------
__global__ void hist_kernel(const int* __restrict__ dst, int* __restrict__ deg, int n_edges) {
  int i = blockIdx.x * blockDim.x + threadIdx.x;
  if (i < n_edges) atomicAdd(&deg[dst[i]], 1);
}

// per-node contiguous region allocation; order irrelevant -> no global scan needed
__global__ void alloc_kernel(const int* __restrict__ deg, int* __restrict__ off,
                             int* __restrict__ counter, int n_nodes) {
  int i = blockIdx.x * blockDim.x + threadIdx.x;
  int lane = threadIdx.x & 63;
  int d = (i < n_nodes) ? deg[i] : 0;
  int pre = d;
  #pragma unroll
  for (int s = 1; s < 64; s <<= 1) {
    int v = __shfl_up(pre, s, 64);
    if (lane >= s) pre += v;
  }
  int tot = __shfl(pre, 63, 64);
  int base = 0;
  if (lane == 0) base = atomicAdd(counter, tot);
  base = __shfl(base, 0, 64);
  if (i < n_nodes) off[i] = base + pre - d;
}

__global__ void scatter_kernel(const int* __restrict__ dst, const int* __restrict__ off,
                               int* __restrict__ pos, int* __restrict__ csr, int n_edges) {
  int i = blockIdx.x * blockDim.x + threadIdx.x;
  if (i < n_edges) {
    int d = dst[i];
    int p = atomicAdd(&pos[d], 1);
    csr[off[d] + p] = i;
  }
}

// ---------------- attention gather: one wave per dst node ----------------
__device__ __forceinline__ float sel8(float v0, float v1, float v2, float v3,
                                      float v4, float v5, float v6, float v7, int idx) {
  float a0 = (idx & 1) ? v1 : v0;
  float a1 = (idx & 1) ? v3 : v2;
  float a2 = (idx & 1) ? v5 : v4;
  float a3 = (idx & 1) ? v7 : v6;
  float b0 = (idx & 2) ? a1 : a0;
  float b1 = (idx & 2) ? a3 : a2;
  return (idx & 4) ? b1 : b0;
}

__global__ __launch_bounds__(256) void attn_kernel(
    const int* __restrict__ src, const int* __restrict__ csr,
    const int* __restrict__ off, const int* __restrict__ deg,
    const float* __restrict__ edge_feat,
    const float* __restrict__ hbuf, const float* __restrict__ subuf,
    const float* __restrict__ svbuf,
    const float* __restrict__ wcc, const float* __restrict__ bcc,
    float* __restrict__ agg, int n_nodes)
{
  __shared__ float pbuf[4][64][8];
  __shared__ int   sbuf[4][64];
  const int wid = threadIdx.x >> 6;
  const int lane = threadIdx.x & 63;
  const long n = (long)blockIdx.x * 4 + wid;
  if (n >= n_nodes) return;
  const int ebase = off[n];
  const int d = deg[n];
  const int hsel = lane & 7;   // head owning output dim `lane` (h.reshape(n, hd, H))

  float svn[8], c0v[8], c1v[8], cbv[8];
  {
    const float4* svp = (const float4*)(svbuf + n*8);
    float4 s0 = svp[0], s1 = svp[1];
    svn[0]=s0.x; svn[1]=s0.y; svn[2]=s0.z; svn[3]=s0.w;
    svn[4]=s1.x; svn[5]=s1.y; svn[6]=s1.z; svn[7]=s1.w;
    #pragma unroll
    for (int hh = 0; hh < 8; ++hh) {
      c0v[hh] = wcc[hh]; c1v[hh] = wcc[8+hh]; cbv[hh] = bcc[hh];
    }
  }
  float m8[8], den8[8];
  #pragma unroll
  for (int hh = 0; hh < 8; ++hh) { m8[hh] = -INFINITY; den8[hh] = 0.f; }
  float msg = 0.f;

  for (int c0 = 0; c0 < d; c0 += 64) {
    const int cnt = min(64, d - c0);
    float sc[8];
    int sid = 0;
    if (lane < cnt) {
      const int eid = csr[ebase + c0 + lane];
      sid = src[eid];
      const float2 ef = *(const float2*)(edge_feat + (long)eid*2);
      const float4* sup = (const float4*)(subuf + (long)sid*8);
      float4 u0 = sup[0], u1 = sup[1];
      float suv[8] = {u0.x,u0.y,u0.z,u0.w,u1.x,u1.y,u1.z,u1.w};
      #pragma unroll
      for (int hh = 0; hh < 8; ++hh) {
        float v = suv[hh] + svn[hh] + ef.x*c0v[hh] + ef.y*c1v[hh] + cbv[hh];
        sc[hh] = (v > 0.f) ? v : 0.2f*v;   // leaky_relu 0.2
      }
    } else {
      #pragma unroll
      for (int hh = 0; hh < 8; ++hh) sc[hh] = -INFINITY;
    }
    // chunk max per head, xor-butterfly => bit-identical replicated across lanes
    float cm[8];
    #pragma unroll
    for (int hh = 0; hh < 8; ++hh) cm[hh] = sc[hh];
    #pragma unroll
    for (int sft = 32; sft >= 1; sft >>= 1) {
      #pragma unroll
      for (int hh = 0; hh < 8; ++hh)
        cm[hh] = fmaxf(cm[hh], __shfl_xor(cm[hh], sft, 64));
    }
    // online softmax update
    float f[8], pv[8];
    #pragma unroll
    for (int hh = 0; hh < 8; ++hh) {
      float nm = fmaxf(m8[hh], cm[hh]);
      f[hh] = __expf(m8[hh] - nm);       // first chunk: exp(-inf)=0 (state is 0 anyway)
      pv[hh] = __expf(sc[hh] - nm);      // idle lanes: exp(-inf)=0
      m8[hh] = nm;
    }
    if (lane < cnt) {
      float4* pp = (float4*)&pbuf[wid][lane][0];
      pp[0] = make_float4(pv[0], pv[1], pv[2], pv[3]);
      pp[1] = make_float4(pv[4], pv[5], pv[6], pv[7]);
      sbuf[wid][lane] = sid;
    }
    // chunk denominator
    float q[8];
    #pragma unroll
    for (int hh = 0; hh < 8; ++hh) q[hh] = pv[hh];
    #pragma unroll
    for (int sft = 32; sft >= 1; sft >>= 1) {
      #pragma unroll
      for (int hh = 0; hh < 8; ++hh)
        q[hh] += __shfl_xor(q[hh], sft, 64);
    }
    #pragma unroll
    for (int hh = 0; hh < 8; ++hh) den8[hh] = den8[hh]*f[hh] + q[hh];
    msg *= sel8(f[0],f[1],f[2],f[3],f[4],f[5],f[6],f[7], hsel);

    // wave-private LDS: waitcnt is sufficient (no cross-wave sharing, no barrier)
    asm volatile("s_waitcnt lgkmcnt(0)" ::: "memory");

    // message accumulation: lane j owns dim j; coalesced 256B h-row reads
    int e2 = 0;
    for (; e2 + 4 <= cnt; e2 += 4) {
      int s0 = sbuf[wid][e2],   s1 = sbuf[wid][e2+1];
      int s2 = sbuf[wid][e2+2], s3 = sbuf[wid][e2+3];
      float p0 = pbuf[wid][e2][hsel],   p1 = pbuf[wid][e2+1][hsel];
      float p2 = pbuf[wid][e2+2][hsel], p3 = pbuf[wid][e2+3][hsel];
      float h0 = hbuf[(long)s0*DIM + lane];
      float h1 = hbuf[(long)s1*DIM + lane];
      float h2 = hbuf[(long)s2*DIM + lane];
      float h3 = hbuf[(long)s3*DIM + lane];
      msg += h0*p0; msg += h1*p1; msg += h2*p2; msg += h3*p3;
    }
    for (; e2 < cnt; ++e2) {
      int s0 = sbuf[wid][e2];
      float p0 = pbuf[wid][e2][hsel];
      msg += hbuf[(long)s0*DIM + lane] * p0;
    }
  }
  float den = sel8(den8[0],den8[1],den8[2],den8[3],den8[4],den8[5],den8[6],den8[7], hsel);
  den = fmaxf(den, 1e-12f);
  agg[n*DIM + lane] = msg / den;
}

// ---------------- FFN: gelu(agg@w1+b1)@w2+b2 ----------------
// Wave per 8 nodes. Phase 1: lane owns 4 hidden cols (j = lane*4..+3); x
// broadcast via v_readlane; w1 row read = coalesced 1KB/instr. hid tile
// (8x256/wave) bounced through wave-private LDS (lgkmcnt only, no barrier).
// Phase 2: lane owns output dim `lane`; hid read uniform (LDS broadcast),
// w2 row read coalesced 256B. Regs: xr[8]+h[8][4]+acc[8] ~ 60 VGPR, no spill.
__global__ __launch_bounds__(256) void ffn_kernel(
    const float* __restrict__ agg,
    const float* __restrict__ w1, const float* __restrict__ b1,
    const float* __restrict__ w2, const float* __restrict__ b2,
    float* __restrict__ out, int n_nodes)
{
  __shared__ float hid[4][8][HIDDEN];   // 32 KB
  const int wid = threadIdx.x >> 6;
  const int lane = threadIdx.x & 63;
  const long nbase = (long)blockIdx.x * 32 + wid * 8;

  float xr[8];
  #pragma unroll
  for (int m = 0; m < 8; ++m) {
    long n = nbase + m; if (n >= n_nodes) n = n_nodes - 1;
    xr[m] = agg[n*DIM + lane];          // coalesced 256B row read
  }
  float4 bb = *(const float4*)(b1 + lane*4);
  float h[8][4];
  #pragma unroll
  for (int m = 0; m < 8; ++m) { h[m][0]=bb.x; h[m][1]=bb.y; h[m][2]=bb.z; h[m][3]=bb.w; }

  #pragma unroll 8
  for (int k = 0; k < 64; ++k) {
    float4 w = *(const float4*)(w1 + k*HIDDEN + lane*4);   // coalesced 1KB
    #pragma unroll
    for (int m = 0; m < 8; ++m) {
      float xk = lane_bcast(xr[m], k);
      h[m][0] += xk*w.x; h[m][1] += xk*w.y; h[m][2] += xk*w.z; h[m][3] += xk*w.w;
    }
  }
  // exact gelu (matches jax approximate=False), then park hid tile in LDS
  #pragma unroll
  for (int m = 0; m < 8; ++m) {
    float4 g;
    g.x = 0.5f*h[m][0]*(1.0f + erff(h[m][0]*0.70710678118654752f));
    g.y = 0.5f*h[m][1]*(1.0f + erff(h[m][1]*0.70710678118654752f));
    g.z = 0.5f*h[m][2]*(1.0f + erff(h[m][2]*0.70710678118654752f));
    g.w = 0.5f*h[m][3]*(1.0f + erff(h[m][3]*0.70710678118654752f));
    *(float4*)&hid[wid][m][lane*4] = g;   // 1KB contiguous per instr, conflict-free
  }
  asm volatile("s_waitcnt lgkmcnt(0)" ::: "memory");  // wave-private LDS: no barrier

  float acc[8];
  const float b2v = b2[lane];
  #pragma unroll
  for (int m = 0; m < 8; ++m) acc[m] = b2v;

  #pragma unroll 8
  for (int j4 = 0; j4 < 64; ++j4) {
    float wa = w2[(j4*4+0)*DIM + lane];   // coalesced 256B rows
    float wb = w2[(j4*4+1)*DIM + lane];
    float wc = w2[(j4*4+2)*DIM + lane];
    float wd = w2[(j4*4+3)*DIM + lane];
    #pragma unroll
    for (int m = 0; m < 8; ++m) {
      float4 hv = *(const float4*)&hid[wid][m][j4*4];   // uniform addr -> broadcast
      acc[m] += hv.x*wa + hv.y*wb + hv.z*wc + hv.w*wd;
    }
  }
  #pragma unroll
  for (int m = 0; m < 8; ++m) {
    long n = nbase + m;
    if (n < n_nodes) out[n*DIM + lane] = acc[m];
  }
}

// ---------------- launch ----------------
extern "C" void kernel_launch(void* const* d_in, const int* in_sizes, int n_in,
                              void* d_out, int out_size, void* d_ws, size_t ws_size,
                              hipStream_t stream)
{
  const float* x         = (const float*)d_in[0];
  const float* edge_feat = (const float*)d_in[1];
  const float* w_in      = (const float*)d_in[2];
  const float* b_in      = (const float*)d_in[3];
  const float* w_edge    = (const float*)d_in[4];
  const float* b_edge    = (const float*)d_in[5];
  const float* w_att_u   = (const float*)d_in[6];
  const float* b_att_u   = (const float*)d_in[7];
  const float* w_att_v   = (const float*)d_in[8];
  const float* w_att_e   = (const float*)d_in[9];
  const float* b_att_e   = (const float*)d_in[10];
  const float* w_ff1     = (const float*)d_in[11];
  const float* b_ff1     = (const float*)d_in[12];
  const float* w_ff2     = (const float*)d_in[13];
  const float* b_ff2     = (const float*)d_in[14];
  const int*   src       = (const int*)d_in[15];
  const int*   dst       = (const int*)d_in[16];
  float* out = (float*)d_out;

  const int n_nodes = in_sizes[0] / DIM;
  const int n_edges = in_sizes[15];

  char* p = (char*)d_ws;
  auto alloc_f = [&](size_t cnt) { float* r = (float*)p; p += ((cnt*4 + 255) & ~(size_t)255); return r; };
  auto alloc_i = [&](size_t cnt) { int* r = (int*)p;   p += ((cnt*4 + 255) & ~(size_t)255); return r; };
  float* Waug  = alloc_f(64*80);
  float* baug  = alloc_f(80);
  float* wcc   = alloc_f(16);
  float* bcc   = alloc_f(8);
  float* hbuf  = alloc_f((size_t)n_nodes*DIM);
  float* subuf = alloc_f((size_t)n_nodes*8);
  float* svbuf = alloc_f((size_t)n_nodes*8);
  float* aggb  = alloc_f((size_t)n_nodes*DIM);
  int* deg     = alloc_i(n_nodes);
  int* pos     = alloc_i(n_nodes);
  int* counter = alloc_i(64);
  int* offb    = alloc_i(n_nodes);
  int* csr     = alloc_i(n_edges);

  // zero deg, pos, counter in one shot (they are contiguous in the layout)
  hipMemsetAsync(deg, 0, (size_t)((char*)offb - (char*)deg), stream);

  hipLaunchKernelGGL(prep_kernel, dim3(1), dim3(256), 0, stream,
      w_in, b_in, w_edge, b_edge, w_att_u, b_att_u, w_att_v, w_att_e, b_att_e,
      Waug, baug, wcc, bcc);

  hipLaunchKernelGGL(node_gemm_kernel, dim3((n_nodes+31)/32), dim3(256), 0, stream,
      x, Waug, baug, hbuf, subuf, svbuf, n_nodes);

  hipLaunchKernelGGL(hist_kernel, dim3((n_edges+255)/256), dim3(256), 0, stream,
      dst, deg, n_edges);
  hipLaunchKernelGGL(alloc_kernel, dim3((n_nodes+255)/256), dim3(256), 0, stream,
      deg, offb, counter, n_nodes);
  hipLaunchKernelGGL(scatter_kernel, dim3((n_edges+255)/256), dim3(256), 0, stream,
      dst, offb, pos, csr, n_edges);

  hipLaunchKernelGGL(attn_kernel, dim3((n_nodes+3)/4), dim3(256), 0, stream,
      src, csr, offb, deg, edge_feat, hbuf, subuf, svbuf, wcc, bcc, aggb, n_nodes);

  hipLaunchKernelGGL(ffn_kernel, dim3((n_nodes+31)/32), dim3(256), 0, stream,
      aggb, w_ff1, b_ff1, w_ff2, b_ff2, out, n_nodes);
}